// Round 1
// baseline (213.147 us; speedup 1.0000x reference)
//
#include <hip/hip_runtime.h>
#include <hip/hip_bf16.h>

using bf16 = __hip_bfloat16;
typedef __bf16 bf16x8 __attribute__((ext_vector_type(8)));
typedef short short4v __attribute__((ext_vector_type(4)));
typedef short short8v __attribute__((ext_vector_type(8)));
typedef float float4v __attribute__((ext_vector_type(4)));

#define DIM   768
#define NH    12
#define HD    64
#define SEQ   2048
#define BATCH 4
#define TOK   (BATCH * SEQ)   // 8192
// softmax scale * log2(e) folded into q at QKV epilogue (flash uses exp2)
#define SCALE_QL2E 0.18033688011112042f

#define NX  (TOK * DIM)        // 6291456
#define NWQ (3 * DIM * DIM)    // 1769472
#define NWP (DIM * DIM)        //  589824

__device__ __forceinline__ short f2bf(float f) {
  union { bf16 h; short s; } u;
  u.h = __float2bfloat16(f);
  return u.s;
}

union frag8 { short4v h[2]; short8v s; bf16x8 b; };

// global(16B) -> LDS async DMA; LDS dest must be wave-uniform base + lane*16B
__device__ __forceinline__ void async_copy16(const bf16* g, short* l) {
  __builtin_amdgcn_global_load_lds(
      (const __attribute__((address_space(1))) unsigned int*)g,
      (__attribute__((address_space(3))) unsigned int*)l, 16, 0, 0);
}

// ---------------------------------------------------------------------------
// Kernel 0: f32 -> bf16 convert for x, w_qkv, w_proj (one fused launch)
// ---------------------------------------------------------------------------
__global__ void __launch_bounds__(256)
cvt3(const float* __restrict__ a, bf16* __restrict__ oa, long na,
     const float* __restrict__ b, bf16* __restrict__ ob, long nb,
     const float* __restrict__ c, bf16* __restrict__ oc, long nc) {
  const long i = ((long)blockIdx.x * 256 + threadIdx.x) * 8;
  const float* src; bf16* dst; long off;
  if (i < na)                { src = a; dst = oa; off = i; }
  else if (i < na + nb)      { src = b; dst = ob; off = i - na; }
  else if (i < na + nb + nc) { src = c; dst = oc; off = i - na - nb; }
  else return;
  const float4v x0 = *(const float4v*)(src + off);
  const float4v x1 = *(const float4v*)(src + off + 4);
  short8v r;
  r[0] = f2bf(x0[0]); r[1] = f2bf(x0[1]); r[2] = f2bf(x0[2]); r[3] = f2bf(x0[3]);
  r[4] = f2bf(x1[0]); r[5] = f2bf(x1[1]); r[6] = f2bf(x1[2]); r[7] = f2bf(x1[3]);
  *(short8v*)(dst + off) = r;
}

// ---------------------------------------------------------------------------
// Shared 128x128 bf16 GEMM main loop (m97 structure) — still used by gemm_proj
// ---------------------------------------------------------------------------
__device__ __forceinline__ void gemm_mainloop(const bf16* __restrict__ A,
                                              const bf16* __restrict__ B,
                                              short* As, short* Bs,
                                              float4v acc[4][4]) {
  const int t = threadIdx.x;
  const int w = t >> 6, l = t & 63, lr = l & 15, q = l >> 4;
  const int wr = ((w >> 1) << 6), wc = ((w & 1) << 6);

  const bf16* Ag = A + (t >> 2) * DIM + (t & 3) * 8;
  const bf16* Bg = B + (t >> 2) * DIM + (t & 3) * 8;

  for (int k0 = 0; k0 < DIM; k0 += 32) {
    __syncthreads();                       // previous tile's consumers done
    async_copy16(Ag,            &As[t * 8]);
    async_copy16(Ag + 64 * DIM, &As[2048 + t * 8]);
    async_copy16(Bg,            &Bs[t * 8]);
    async_copy16(Bg + 64 * DIM, &Bs[2048 + t * 8]);
    Ag += 32; Bg += 32;
    __syncthreads();                       // vmcnt(0) drain before barrier

    bf16x8 af[4], bfv[4];
#pragma unroll
    for (int i = 0; i < 4; ++i)
      af[i] = *(const bf16x8*)&As[(wr + i * 16 + lr) * 32 + q * 8];
#pragma unroll
    for (int j = 0; j < 4; ++j)
      bfv[j] = *(const bf16x8*)&Bs[(wc + j * 16 + lr) * 32 + q * 8];
#pragma unroll
    for (int i = 0; i < 4; ++i)
#pragma unroll
      for (int j = 0; j < 4; ++j)
        acc[i][j] = __builtin_amdgcn_mfma_f32_16x16x32_bf16(af[i], bfv[j],
                                                            acc[i][j], 0, 0, 0);
  }
}

// ---------------------------------------------------------------------------
// Kernel 1: QKV projection — 256x256 tile, BK=64, 8 waves, 8-phase counted-
// vmcnt schedule (T1+T2+T3+T4+T5 per the catalog; m201 template geometry).
//
// LDS: 2 bufs x 4 slots (A-half0, A-half1, B-half0, B-half1), each slot a
// 128-row x 64-K half-tile stored as 2 K-panels of [128][32] bf16.  Within a
// panel, the element col is XOR-swizzled by row bits 3 and 1
// (c' = c ^ bit3(r)*16 ^ bit1(r)*8, 8-elem granularity): ds_read_b128 of 16
// consecutive rows then lands 2-way per bank-group (free, m136), vs 16-way
// linear.  global_load_lds requires a LINEAR LDS dest, so the swizzle is
// applied as the (involutive) inverse on the per-lane GLOBAL source address
// (rule #21: both-sides-or-neither).
//
// Frag interleave: wave (wm = w>>2, wn = w&3); m-frag mf -> tile row
// mf*32 + wm*16 (+lr); n-frag nf -> tile col nf*64 + wn*16 (+lr).  So frags
// 0-3 live entirely in half 0, frags 4-7 in half 1, making half-tiles
// retire phase-by-phase (required for the 1-half-tile-per-phase staging).
//
// Per K-tile (4 phases, quadrants): ph1 reads A0-frags+B0-frags (12 ds_read),
// ph2 reads B1-frags (4), ph3 reads A1-frags (8), ph4 reads none.  Each phase:
// {ds_read | stage 1 half-tile (2x global_load_lds) | barrier | lgkmcnt(0) |
// setprio(1) 16xMFMA setprio(0) | [vmcnt(6) at ph4/ph8] | barrier}.
// Steady-state stage targets (1/phase):  ph1: buf1.A1(tile 2i+1),
// ph2: buf0.A0(2i+2), ph3: buf0.B0, ph4: buf0.B1, ph5: buf0.A1,
// ph6: buf1.A0(2i+3), ph7: buf1.B0, ph8: buf1.B1.  vmcnt(6) = 3 half-tiles
// in flight x 2 loads; slot overwritten exactly 2 barriers after last read.
// ---------------------------------------------------------------------------
#define STG(gp, c, slot, k0)                                                  \
  async_copy16((gp) + (k0),      &lds[c][slot][t * 8]);                       \
  async_copy16((gp) + (k0) + 32, &lds[c][slot][4096 + t * 8])

#define RD_A(dst, C, slot)                                                    \
  _Pragma("unroll") for (int f_ = 0; f_ < 4; ++f_) {                          \
    dst[f_][0] = *(const bf16x8*)&lds[C][slot][f_ * 1024 + arow32 + acol];    \
    dst[f_][1] = *(const bf16x8*)&lds[C][slot][4096 + f_ * 1024 + arow32 + acol]; \
  }

#define RD_B(dst, C, slot)                                                    \
  _Pragma("unroll") for (int g_ = 0; g_ < 2; ++g_) {                          \
    dst[g_][0] = *(const bf16x8*)&lds[C][slot][g_ * 2048 + brow32 + acol];    \
    dst[g_][1] = *(const bf16x8*)&lds[C][slot][4096 + g_ * 2048 + brow32 + acol]; \
  }

#define MFMA8(AF, BF, MO, NO)                                                 \
  _Pragma("unroll") for (int f_ = 0; f_ < 4; ++f_)                            \
  _Pragma("unroll") for (int g_ = 0; g_ < 2; ++g_) {                          \
    acc[(MO) + f_][(NO) + g_] = __builtin_amdgcn_mfma_f32_16x16x32_bf16(      \
        AF[f_][0], BF[g_][0], acc[(MO) + f_][(NO) + g_], 0, 0, 0);            \
    acc[(MO) + f_][(NO) + g_] = __builtin_amdgcn_mfma_f32_16x16x32_bf16(      \
        AF[f_][1], BF[g_][1], acc[(MO) + f_][(NO) + g_], 0, 0, 0);            \
  }

#define BARRIER __builtin_amdgcn_s_barrier()
#define LGKM0 asm volatile("s_waitcnt lgkmcnt(0)" ::: "memory")
#define VW6 asm volatile("s_waitcnt vmcnt(6)" ::: "memory")
#define VW0 asm volatile("s_waitcnt vmcnt(0)" ::: "memory")
#define NOSTG (void)0

#define KTILE(C, ST1, ST2, ST3, ST4, VW)                                      \
  {                                                                           \
    bf16x8 a0[4][2], a1[4][2], b0[2][2], b1[2][2];                            \
    RD_A(a0, C, 0); RD_B(b0, C, 2);                                           \
    ST1; BARRIER; LGKM0;                                                      \
    __builtin_amdgcn_s_setprio(1); MFMA8(a0, b0, 0, 0);                       \
    __builtin_amdgcn_s_setprio(0); BARRIER;                                   \
    RD_B(b1, C, 3);                                                           \
    ST2; BARRIER; LGKM0;                                                      \
    __builtin_amdgcn_s_setprio(1); MFMA8(a0, b1, 0, 2);                       \
    __builtin_amdgcn_s_setprio(0); BARRIER;                                   \
    RD_A(a1, C, 1);                                                           \
    ST3; BARRIER; LGKM0;                                                      \
    __builtin_amdgcn_s_setprio(1); MFMA8(a1, b0, 4, 0);                       \
    __builtin_amdgcn_s_setprio(0); BARRIER;                                   \
    ST4; BARRIER;                                                             \
    __builtin_amdgcn_s_setprio(1); MFMA8(a1, b1, 4, 2);                       \
    __builtin_amdgcn_s_setprio(0); VW; BARRIER;                               \
  }

__global__ void __launch_bounds__(512, 2)
gemm_qkv(const bf16* __restrict__ X, const bf16* __restrict__ W,
         const float* __restrict__ bias,
         bf16* __restrict__ qb, bf16* __restrict__ kb, bf16* __restrict__ vb) {
  __shared__ short lds[2][4][8192];   // 128 KiB
  const int t = threadIdx.x;
  const int w = t >> 6, l = t & 63, lr = l & 15, q = l >> 4;
  const int wm = w >> 2, wn = w & 3;

  // XCD-aware bijective swizzle: 288 blocks, 288 % 8 == 0, 36 blocks/XCD.
  // row-major decode -> each XCD owns 4 tile-rows x all 9 tile-cols (L2 reuse)
  const int orig = blockIdx.x;
  const int swz = (orig & 7) * 36 + (orig >> 3);
  const int tm = swz / 9, tn = swz - tm * 9;
  const int row0 = tm * 256, col0 = tn * 256;

  // staging coords: thread t covers half-tile row sr = t>>2, 8 elems; the
  // global col carries the inverse LDS swizzle (involution, same XOR)
  const int sr = t >> 2;
  const int sswz = (((sr >> 3) & 1) << 4) | (((sr >> 1) & 1) << 3);
  const int scol = (((t & 3) << 3) ^ sswz);
  const bf16* pa0 = X + (size_t)(row0 +       sr) * DIM + scol;
  const bf16* pa1 = X + (size_t)(row0 + 128 + sr) * DIM + scol;
  const bf16* pb0 = W + (size_t)(col0 +       sr) * DIM + scol;
  const bf16* pb1 = W + (size_t)(col0 + 128 + sr) * DIM + scol;

  // fragment-read coords: frag row = <frag base> + lr; swizzle bits 1,3 of
  // the row come from lr only, so the XOR term is per-thread constant
  const int rswz = (((lr >> 3) & 1) << 4) | (((lr >> 1) & 1) << 3);
  const int acol = ((q << 3) ^ rswz);
  const int arow32 = (wm * 16 + lr) * 32;
  const int brow32 = (wn * 16 + lr) * 32;

  float4v acc[8][4] = {};

  // prologue: tile0 -> buf0 (all 4 slots), tile1 -> buf1 (A0,B0,B1).
  // vmcnt(6) leaves the 3 buf1 stages in flight; oldest 8 loads (= buf0) done.
  STG(pa0, 0, 0, 0);
  STG(pb0, 0, 2, 0);
  STG(pb1, 0, 3, 0);
  STG(pa1, 0, 1, 0);
  STG(pa0, 1, 0, 64);
  STG(pb0, 1, 2, 64);
  STG(pb1, 1, 3, 64);
  asm volatile("s_waitcnt vmcnt(6)" ::: "memory");
  BARRIER;

#pragma unroll 1
  for (int i = 0; i < 5; ++i) {
    // pointers sit at K-offset 128*i; tile 2i+1 = +64, 2i+2 = +128, 2i+3 = +192
    KTILE(0, STG(pa1, 1, 1, 64),  STG(pa0, 0, 0, 128),
             STG(pb0, 0, 2, 128), STG(pb1, 0, 3, 128), VW6);
    KTILE(1, STG(pa1, 0, 1, 128), STG(pa0, 1, 0, 192),
             STG(pb0, 1, 2, 192), STG(pb1, 1, 3, 192), VW6);
    pa0 += 128; pa1 += 128; pb0 += 128; pb1 += 128;
  }
  // epilogue: tiles 10 (buf0) & 11 (buf1); ph1 still stages buf1.A1 (tile 11,
  // k=704); drain vmcnt(0) at ph4 before buf1 is consumed.
  KTILE(0, STG(pa1, 1, 1, 64), NOSTG, NOSTG, NOSTG, VW0);
  KTILE(1, NOSTG, NOSTG, NOSTG, NOSTG, NOSTG);

  // C-write epilogue: rows row0 + mf*32 + wm*16 + q*4 + r ; cols
  // col0 + nf*64 + wn*16 + lr.  Same q/k/v scatter as before.
#pragma unroll
  for (int nf = 0; nf < 4; ++nf) {
    const int gn = col0 + nf * 64 + wn * 16 + lr;   // 0..2303
    const int which = gn / DIM;                     // uniform per 16-lane frag
    const int cc = gn - which * DIM;
    const int hh = cc >> 6, dd = cc & 63;
    const float bv = bias[gn];
#pragma unroll
    for (int mf = 0; mf < 8; ++mf) {
      const int gm0 = row0 + mf * 32 + wm * 16 + (q << 2);  // token base (x4)
      const int b = gm0 >> 11, n0 = gm0 & 2047;
      if (which == 2) {
        short4v pv;
#pragma unroll
        for (int r = 0; r < 4; ++r) pv[r] = f2bf(acc[mf][nf][r] + bv);
        *(short4v*)&vb[((size_t)(b * NH + hh) * HD + dd) * SEQ + n0] = pv;
      } else {
        bf16* dst = (which == 0) ? qb : kb;
        const float sc = (which == 0) ? SCALE_QL2E : 1.0f;
#pragma unroll
        for (int r = 0; r < 4; ++r)
          dst[((size_t)(b * NH + hh) * SEQ + n0 + r) * HD + dd] =
              __float2bfloat16((acc[mf][nf][r] + bv) * sc);
      }
    }
  }
}

// ---------------------------------------------------------------------------
// Kernel 2: flash attention — r6 tile structure, NO-MAX streaming softmax.
// (unchanged this round)
// ---------------------------------------------------------------------------
__global__ void __launch_bounds__(256, 3)
flash_attn(const bf16* __restrict__ Qp, const bf16* __restrict__ Kp,
           const bf16* __restrict__ Vtp, bf16* __restrict__ Op) {
  const int bh = blockIdx.y, qt = blockIdx.x;
  const int t = threadIdx.x, w = t >> 6, l = t & 63, lr = l & 15, q = l >> 4;
  __shared__ short Ks[128 * 72];   // K tile [kk][d], padded 64->72
  __shared__ short Vt[64 * 136];   // V^T tile [d][kk], padded 128->136

  const bf16* Qb = Qp  + (size_t)(bh * SEQ + qt * 128) * HD;
  const bf16* Kb = Kp  + (size_t)bh * SEQ * HD;
  const bf16* Vb = Vtp + (size_t)bh * HD * SEQ;   // [d][n]

  const int tr3 = t >> 3, td8 = (t & 7) * 8;     // K staging coords
  const int tr4 = t >> 4, tc8 = (t & 15) * 8;    // V^T staging coords

  // prefetch K/V tile 0 into registers
  short8v kr[4], vr[4];
#pragma unroll
  for (int i = 0; i < 4; ++i) {
    kr[i] = *(const short8v*)(Kb + (size_t)(i * 32 + tr3) * HD + td8);
    vr[i] = *(const short8v*)(Vb + (size_t)(i * 16 + tr4) * SEQ + tc8);
  }

  // stage Q tile [128][64] into Ks, read per-wave Q fragments
#pragma unroll
  for (int i = 0; i < 4; ++i)
    *(short8v*)&Ks[(i * 32 + tr3) * 72 + td8] =
        *(const short8v*)(Qb + (size_t)(i * 32 + tr3) * HD + td8);
  __syncthreads();
  bf16x8 qf[2][2];
#pragma unroll
  for (int it = 0; it < 2; ++it)
#pragma unroll
    for (int kq = 0; kq < 2; ++kq)
      qf[it][kq] = *(const bf16x8*)&Ks[(w * 32 + it * 16 + lr) * 72 + kq * 32 + q * 8];

  float4v o[2][4] = {};
  float l_run[2] = {0.f, 0.f};     // per-lane partial row sums (deferred)

  for (int kt = 0; kt < 16; ++kt) {
    __syncthreads();                 // previous tile's LDS consumers done
#pragma unroll
    for (int i = 0; i < 4; ++i) {
      *(short8v*)&Ks[(i * 32 + tr3) * 72 + td8]  = kr[i];
      *(short8v*)&Vt[(i * 16 + tr4) * 136 + tc8] = vr[i];
    }
    __syncthreads();
    if (kt < 15) {                   // prefetch next tile (overlaps compute)
      const int k1 = (kt + 1) * 128;
#pragma unroll
      for (int i = 0; i < 4; ++i) {
        kr[i] = *(const short8v*)(Kb + (size_t)(k1 + i * 32 + tr3) * HD + td8);
        vr[i] = *(const short8v*)(Vb + (size_t)(i * 16 + tr4) * SEQ + k1 + tc8);
      }
    }

    // S^T = K * Q^T : tiles [kk 8][qr 2]
    float4v s[8][2] = {};
#pragma unroll
    for (int jn = 0; jn < 8; ++jn) {
      bf16x8 kf[2];
#pragma unroll
      for (int kq = 0; kq < 2; ++kq)
        kf[kq] = *(const bf16x8*)&Ks[(jn * 16 + lr) * 72 + kq * 32 + q * 8];
#pragma unroll
      for (int it = 0; it < 2; ++it)
#pragma unroll
        for (int kq = 0; kq < 2; ++kq)
          s[jn][it] = __builtin_amdgcn_mfma_f32_16x16x32_bf16(kf[kq], qf[it][kq],
                                                              s[jn][it], 0, 0, 0);
    }

    // streaming softmax numerator: p = exp2(s), per-lane l partial, pack P
    frag8 pf[4][2];
#pragma unroll
    for (int it = 0; it < 2; ++it) {
      float ls = 0.f;
#pragma unroll
      for (int jn = 0; jn < 8; ++jn)
#pragma unroll
        for (int r = 0; r < 4; ++r) {
          const float p = __builtin_amdgcn_exp2f(s[jn][it][r]);
          s[jn][it][r] = p;
          ls += p;
        }
      l_run[it] += ls;
      // pack P pairs: slot (q,j) <-> kk = 32c + 16*(j>>2) + 4q + (j&3)
#pragma unroll
      for (int c4 = 0; c4 < 4; ++c4) {
#pragma unroll
        for (int r = 0; r < 4; ++r) {
          pf[c4][it].s[r]     = f2bf(s[2 * c4][it][r]);
          pf[c4][it].s[4 + r] = f2bf(s[2 * c4 + 1][it][r]);
        }
      }
    }

    // O += P * V  (16x16x32, B mirrors the paired-k slot mapping)
#pragma unroll
    for (int c4 = 0; c4 < 4; ++c4) {
#pragma unroll
      for (int dj = 0; dj < 4; ++dj) {
        frag8 vf;
        vf.h[0] = *(const short4v*)&Vt[(dj * 16 + lr) * 136 + c4 * 32 + (q << 2)];
        vf.h[1] = *(const short4v*)&Vt[(dj * 16 + lr) * 136 + c4 * 32 + 16 + (q << 2)];
#pragma unroll
        for (int it = 0; it < 2; ++it)
          o[it][dj] = __builtin_amdgcn_mfma_f32_16x16x32_bf16(pf[c4][it].b, vf.b,
                                                              o[it][dj], 0, 0, 0);
      }
    }
  }

  // epilogue: reduce l across the 4 quads (once), O /= l, coalesced-ish store
  const int b = bh / NH, h = bh - b * NH;
#pragma unroll
  for (int it = 0; it < 2; ++it) {
    l_run[it] += __shfl_xor(l_run[it], 16);
    l_run[it] += __shfl_xor(l_run[it], 32);
    const float li = 1.0f / l_run[it];   // valid at lane qr = lr
#pragma unroll
    for (int r = 0; r < 4; ++r) {
      const float linv = __shfl(li, (q << 2) + r, 64);
      const int grow = b * SEQ + qt * 128 + w * 32 + it * 16 + (q << 2) + r;
      bf16* orow = Op + (size_t)grow * DIM + h * HD;
#pragma unroll
      for (int dj = 0; dj < 4; ++dj)
        orow[dj * 16 + lr] = __float2bfloat16(o[it][dj][r] * linv);
    }
  }
}

// ---------------------------------------------------------------------------
// Kernel 3: output projection.  AO[8192,768](bf16) @ w_proj^T(bf16) + b -> f32
// (unchanged this round)
// ---------------------------------------------------------------------------
__global__ void __launch_bounds__(256)
gemm_proj(const bf16* __restrict__ A, const bf16* __restrict__ W,
          const float* __restrict__ bias, float* __restrict__ out) {
  __shared__ short As[128 * 32];
  __shared__ short Bs[128 * 32];
  const int t = threadIdx.x;
  const int w = t >> 6, l = t & 63, lr = l & 15, q = l >> 4;
  const int wr = ((w >> 1) << 6), wc = ((w & 1) << 6);
  const int row0 = blockIdx.y * 128, col0 = blockIdx.x * 128;

  float4v acc[4][4] = {};
  gemm_mainloop(A + row0 * DIM, W + col0 * DIM, As, Bs, acc);

#pragma unroll
  for (int j = 0; j < 4; ++j) {
    const int gn = col0 + wc + j * 16 + lr;
    const float bv = bias[gn];
#pragma unroll
    for (int i = 0; i < 4; ++i) {
#pragma unroll
      for (int r = 0; r < 4; ++r) {
        const int gm = row0 + wr + i * 16 + (q << 2) + r;
        out[(size_t)gm * DIM + gn] = acc[i][j][r] + bv;
      }
    }
  }
}

// ---------------------------------------------------------------------------
extern "C" void kernel_launch(void* const* d_in, const int* in_sizes, int n_in,
                              void* d_out, int out_size, void* d_ws, size_t ws_size,
                              hipStream_t stream) {
  const float* x      = (const float*)d_in[0];
  const float* w_qkv  = (const float*)d_in[1];
  const float* b_qkv  = (const float*)d_in[2];
  const float* w_proj = (const float*)d_in[3];
  const float* b_proj = (const float*)d_in[4];
  float* out = (float*)d_out;

  const size_t perbuf = (size_t)BATCH * NH * SEQ * HD;  // 6291456 elems
  bf16* qb  = (bf16*)d_ws;
  bf16* kb  = qb + perbuf;
  bf16* vb  = kb + perbuf;          // [B,H,64,N] transposed
  bf16* ao  = vb + perbuf;
  bf16* xb  = ao + perbuf;          // NX
  bf16* wqb = xb + (size_t)NX;      // NWQ
  bf16* wpb = wqb + (size_t)NWQ;    // NWP

  const int cvt_blocks = (NX + NWQ + NWP) / 8 / 256;   // 4224
  cvt3<<<cvt_blocks, 256, 0, stream>>>(x, xb, NX, w_qkv, wqb, NWQ, w_proj, wpb, NWP);
  gemm_qkv <<<dim3(288), 512, 0, stream>>>(xb, wqb, b_qkv, qb, kb, vb);
  flash_attn<<<dim3(SEQ / 128, BATCH * NH), 256, 0, stream>>>(qb, kb, vb, ao);
  gemm_proj <<<dim3(DIM / 128, TOK / 128),  256, 0, stream>>>(ao, wpb, b_proj, out);
}